// Round 1
// baseline (1533.248 us; speedup 1.0000x reference)
//
#include <hip/hip_runtime.h>

#define CDIM 64
#define KCODES 1024
#define SPATIAL 32768          // 32*32*32
#define NPOS 65536             // B * SPATIAL
#define NEL 4194304            // 2*64*32768

// d_out layout (floats), outputs concatenated in reference return order
#define OUT_Q    0
#define OUT_LOSS 4194304
#define OUT_IDX  4194305
#define OUT_SUM  4259841
#define OUT_EMB  4260097

// ---------------- ||e_k||^2 precompute ----------------
__global__ void enorm_kernel(const float* __restrict__ emb, float* __restrict__ enorm) {
    int k = blockIdx.x * blockDim.x + threadIdx.x;
    if (k >= KCODES) return;
    const float4* e4 = reinterpret_cast<const float4*>(emb + (size_t)k * CDIM);
    float s = 0.f;
#pragma unroll
    for (int i = 0; i < CDIM / 4; ++i) {
        float4 v = e4[i];
        s = fmaf(v.x, v.x, s);
        s = fmaf(v.y, v.y, s);
        s = fmaf(v.z, v.z, s);
        s = fmaf(v.w, v.w, s);
    }
    enorm[k] = s;
}

// ---------------- zero loss + encodings_sum ----------------
__global__ void init_kernel(float* __restrict__ out) {
    int t = blockIdx.x * blockDim.x + threadIdx.x;
    if (t == 0) out[OUT_LOSS] = 0.f;
    if (t < 256) out[OUT_SUM + t] = 0.f;
}

// ---------------- main VQ kernel ----------------
// Block: 256 threads = 4 waves. Each block owns 64 consecutive positions.
// Wave w scans codes [w*256, w*256+256). LDS min-reduce, wave 0 epilogue.
__global__ __launch_bounds__(256, 4) void vq_kernel(
        const float* __restrict__ in, const float* __restrict__ emb,
        const float* __restrict__ enorm, float* __restrict__ out) {
    const int lane = threadIdx.x & 63;
    const int wv   = threadIdx.x >> 6;          // 0..3: k-chunk
    const int n    = blockIdx.x * 64 + lane;    // position id
    const int b    = n >> 15;
    const int s    = n & 32767;
    const float* xin = in + (size_t)b * CDIM * SPATIAL + s;

    // load x[64] into registers (coalesced per-c across the 64 lanes)
    float x[CDIM];
#pragma unroll
    for (int c = 0; c < CDIM; ++c) x[c] = xin[(size_t)c * SPATIAL];

    // scan this wave's 256 codes; score = ||e||^2 - 2*x.e  (x^2 term constant)
    float best = 3.4e38f;
    int   bidx = 0;
    const int k0 = wv * (KCODES / 4);
    for (int k = k0; k < k0 + KCODES / 4; k += 2) {
        const float* e0 = emb + (size_t)k * CDIM;   // wave-uniform -> s_load
        const float* e1 = e0 + CDIM;
        float a0 = 0.f, a1 = 0.f, a2 = 0.f, a3 = 0.f;
        float b0 = 0.f, b1 = 0.f, b2 = 0.f, b3 = 0.f;
#pragma unroll
        for (int c = 0; c < CDIM; c += 4) {
            a0 = fmaf(e0[c + 0], x[c + 0], a0);
            a1 = fmaf(e0[c + 1], x[c + 1], a1);
            a2 = fmaf(e0[c + 2], x[c + 2], a2);
            a3 = fmaf(e0[c + 3], x[c + 3], a3);
            b0 = fmaf(e1[c + 0], x[c + 0], b0);
            b1 = fmaf(e1[c + 1], x[c + 1], b1);
            b2 = fmaf(e1[c + 2], x[c + 2], b2);
            b3 = fmaf(e1[c + 3], x[c + 3], b3);
        }
        float d0 = (a0 + a1) + (a2 + a3);
        float d1 = (b0 + b1) + (b2 + b3);
        float s0 = fmaf(-2.f, d0, enorm[k]);
        float s1 = fmaf(-2.f, d1, enorm[k + 1]);
        if (s0 < best) { best = s0; bidx = k; }       // strict < keeps first min
        if (s1 < best) { best = s1; bidx = k + 1; }
    }

    // min-reduce across the 4 waves
    __shared__ float lscore[4][64];
    __shared__ int   lidx[4][64];
    lscore[wv][lane] = best;
    lidx[wv][lane]   = bidx;
    __syncthreads();

    if (wv == 0) {
        float gb = lscore[0][lane];
        int   gi = lidx[0][lane];
#pragma unroll
        for (int w = 1; w < 4; ++w) {
            float sc = lscore[w][lane];
            int   ix = lidx[w][lane];
            if (sc < gb) { gb = sc; gi = ix; }        // ascending w => lower k wins ties
        }
        out[OUT_IDX + n] = (float)gi;                  // index as float

        const float* eb = emb + (size_t)gi * CDIM;     // lane-divergent gather (L2-hit)
        float* qo = out + OUT_Q + (size_t)b * CDIM * SPATIAL + s;
        float lsum = 0.f;
#pragma unroll
        for (int c = 0; c < CDIM; ++c) {
            float e = eb[c];
            float d = e - x[c];                        // stop_grad(q - x)
            lsum = fmaf(d, d, lsum);
            qo[(size_t)c * SPATIAL] = x[c] + d;        // exact reference formula x+(q-x)
        }
        // wave-level sum over the 64 lanes
#pragma unroll
        for (int off = 32; off > 0; off >>= 1) lsum += __shfl_down(lsum, off);
        if (lane == 0)
            atomicAdd(out + OUT_LOSS, lsum * (0.25f / (float)NEL));
    }
}

extern "C" void kernel_launch(void* const* d_in, const int* in_sizes, int n_in,
                              void* d_out, int out_size, void* d_ws, size_t ws_size,
                              hipStream_t stream) {
    const float* in  = (const float*)d_in[0];   // [2,64,32,32,32] f32
    const float* emb = (const float*)d_in[1];   // [1024,64] f32
    float* out   = (float*)d_out;
    float* enorm = (float*)d_ws;                // 1024 floats scratch

    enorm_kernel<<<KCODES / 256, 256, 0, stream>>>(emb, enorm);
    init_kernel<<<1, 256, 0, stream>>>(out);
    vq_kernel<<<NPOS / 64, 256, 0, stream>>>(in, emb, enorm, out);

    // embedding passthrough output
    hipMemcpyAsync(out + OUT_EMB, emb, (size_t)KCODES * CDIM * sizeof(float),
                   hipMemcpyDeviceToDevice, stream);
}

// Round 2
// 93.313 us; speedup vs baseline: 16.4313x; 16.4313x over previous
//
#include <hip/hip_runtime.h>
#include <stdint.h>

#define KCODES  1024
#define CDIM    64
#define SPATIAL 32768
#define NPOS    65536
#define NEL     4194304

// d_out layout (floats), outputs concatenated in reference return order
#define OUT_Q    0
#define OUT_LOSS 4194304
#define OUT_IDX  4194305
#define OUT_SUM  4259841
#define OUT_EMB  4260097

// codebook ws record: per 128-code chunk: hi frags 16KB | lo frags 16KB | -0.5*||e||^2 512B
#define REC_BYTES 33280
#define NCHUNK    8

typedef _Float16 half8 __attribute__((ext_vector_type(8)));
typedef float    f32x4 __attribute__((ext_vector_type(4)));

// ---------------- codebook -> fragment-ready hi/lo fp16 + (-0.5*||e||^2) ----------------
__global__ void prep_emb(const float* __restrict__ emb, char* __restrict__ ws) {
    int k = blockIdx.x * blockDim.x + threadIdx.x;
    if (k >= KCODES) return;
    const float* e = emb + (size_t)k * CDIM;
    int ch = k >> 7, mt = (k >> 4) & 7, row = k & 15;
    char* rec = ws + (size_t)ch * REC_BYTES;
    _Float16* hi = (_Float16*)rec;
    _Float16* lo = hi + 8192;
    float* ens = (float*)(rec + 32768);
    float s2 = 0.f;
    for (int c = 0; c < CDIM; ++c) {
        float v = e[c];
        s2 = fmaf(v, v, s2);
        _Float16 h = (_Float16)v;
        _Float16 l = (_Float16)(v - (float)h);
        int s = c >> 5, g = (c >> 3) & 3, i = c & 7;
        // lane-linear layout: lane = g*16+row, frag elem i
        int off = (mt * 2 + s) * 512 + ((g << 4) | row) * 8 + i;
        hi[off] = h;
        lo[off] = l;
    }
    ens[k & 127] = -0.5f * s2;
}

// ---------------- zero loss + encodings_sum ----------------
__global__ void init_kernel(float* __restrict__ out) {
    int t = blockIdx.x * blockDim.x + threadIdx.x;
    if (t == 0) out[OUT_LOSS] = 0.f;
    if (t < 256) out[OUT_SUM + t] = 0.f;
}

// ---------------- main VQ kernel ----------------
// Block: 256 thr = 4 waves, 128 positions (32/wave = 2 N-tiles of 16).
// Each wave scans all 1024 codes via 16x16x32 f16 MFMA, fp16 2-way split (3 terms).
// Score = x.e - 0.5||e||^2 (C-init), argmax == argmin distance.
__global__ __launch_bounds__(256) void vq_kernel(
        const float* __restrict__ in, const float* __restrict__ emb,
        const char* __restrict__ wsA, float* __restrict__ out) {
    __shared__ __align__(16) char smem[33280];
    const int tid  = threadIdx.x;
    const int lane = tid & 63, wv = tid >> 6;
    const int g = lane >> 4, col = lane & 15;
    const int p0 = blockIdx.x * 128;          // block's global position base
    const int b  = p0 >> 15;                  // batch (tile never straddles)
    const int s0 = p0 & 32767;
    const float* xin = in + (size_t)b * (CDIM * SPATIAL) + s0;

    // ---- phase A: x tile [128 pos][64 c] -> LDS as packed (hi,lo) half2, stride 65 ----
    uint32_t* xl = (uint32_t*)smem;
    {
        int p = tid & 127, chalf = tid >> 7;
#pragma unroll
        for (int c = chalf * 32; c < chalf * 32 + 32; ++c) {
            float v = xin[(size_t)c * SPATIAL + p];     // coalesced across lanes
            _Float16 h = (_Float16)v;
            _Float16 l = (_Float16)(v - (float)h);
            union { uint32_t u; _Float16 f[2]; } cv;
            cv.f[0] = h; cv.f[1] = l;
            xl[p * 65 + c] = cv.u;
        }
    }
    __syncthreads();

    // ---- phase B: B-fragments (positions) into registers ----
    half8 bh[2][2], bl[2][2];
#pragma unroll
    for (int t = 0; t < 2; ++t)
#pragma unroll
        for (int s = 0; s < 2; ++s) {
            int prow = wv * 32 + t * 16 + col;
            const uint32_t* src = xl + prow * 65 + s * 32 + g * 8;
#pragma unroll
            for (int i = 0; i < 8; ++i) {
                union { uint32_t u; _Float16 f[2]; } cv;
                cv.u = src[i];
                bh[t][s][i] = cv.f[0];
                bl[t][s][i] = cv.f[1];
            }
        }
    __syncthreads();

    // ---- main loop over 8 codebook chunks (128 codes each), reg-staged ----
    float best[2][4];
    int   bmt[2][4];
#pragma unroll
    for (int t = 0; t < 2; ++t)
#pragma unroll
        for (int r = 0; r < 4; ++r) { best[t][r] = -3.402823466e38f; bmt[t][r] = 0; }

    // prefetch chunk 0 into registers (linear copy: 256 thr x 8 x 16B + ens)
    uint4 st[8];
    float ensr = 0.f;
    {
        const char* src = wsA;
#pragma unroll
        for (int j = 0; j < 8; ++j)
            st[j] = *(const uint4*)(src + j * 4096 + tid * 16);
        if (tid < 128) ensr = *(const float*)(src + 32768 + tid * 4);
    }

    for (int ch = 0; ch < NCHUNK; ++ch) {
        __syncthreads();   // previous chunk's LDS readers done (and phase-B at ch=0)
#pragma unroll
        for (int j = 0; j < 8; ++j)
            *(uint4*)(smem + j * 4096 + tid * 16) = st[j];
        if (tid < 128) ((float*)(smem + 32768))[tid] = ensr;
        if (ch < NCHUNK - 1) {  // issue next-chunk loads; no LDS dep -> fly under compute
            const char* src = wsA + (size_t)(ch + 1) * REC_BYTES;
#pragma unroll
            for (int j = 0; j < 8; ++j)
                st[j] = *(const uint4*)(src + j * 4096 + tid * 16);
            if (tid < 128) ensr = *(const float*)(src + 32768 + tid * 4);
        }
        __syncthreads();   // staged chunk visible

        const _Float16* Ah  = (const _Float16*)smem;
        const _Float16* Al  = Ah + 8192;
        const float*    ens = (const float*)(smem + 32768);
#pragma unroll
        for (int mt = 0; mt < 8; ++mt) {
            half8 ah0 = *(const half8*)(Ah + (mt * 2 + 0) * 512 + lane * 8);
            half8 ah1 = *(const half8*)(Ah + (mt * 2 + 1) * 512 + lane * 8);
            half8 al0 = *(const half8*)(Al + (mt * 2 + 0) * 512 + lane * 8);
            half8 al1 = *(const half8*)(Al + (mt * 2 + 1) * 512 + lane * 8);
            f32x4 ei  = *(const f32x4*)(ens + mt * 16 + g * 4);   // -0.5||e||^2 per row
            f32x4 a0 = ei, a1 = ei;
            a0 = __builtin_amdgcn_mfma_f32_16x16x32_f16(ah0, bh[0][0], a0, 0, 0, 0);
            a0 = __builtin_amdgcn_mfma_f32_16x16x32_f16(ah1, bh[0][1], a0, 0, 0, 0);
            a0 = __builtin_amdgcn_mfma_f32_16x16x32_f16(ah0, bl[0][0], a0, 0, 0, 0);
            a0 = __builtin_amdgcn_mfma_f32_16x16x32_f16(ah1, bl[0][1], a0, 0, 0, 0);
            a0 = __builtin_amdgcn_mfma_f32_16x16x32_f16(al0, bh[0][0], a0, 0, 0, 0);
            a0 = __builtin_amdgcn_mfma_f32_16x16x32_f16(al1, bh[0][1], a0, 0, 0, 0);
            a1 = __builtin_amdgcn_mfma_f32_16x16x32_f16(ah0, bh[1][0], a1, 0, 0, 0);
            a1 = __builtin_amdgcn_mfma_f32_16x16x32_f16(ah1, bh[1][1], a1, 0, 0, 0);
            a1 = __builtin_amdgcn_mfma_f32_16x16x32_f16(ah0, bl[1][0], a1, 0, 0, 0);
            a1 = __builtin_amdgcn_mfma_f32_16x16x32_f16(ah1, bl[1][1], a1, 0, 0, 0);
            a1 = __builtin_amdgcn_mfma_f32_16x16x32_f16(al0, bh[1][0], a1, 0, 0, 0);
            a1 = __builtin_amdgcn_mfma_f32_16x16x32_f16(al1, bh[1][1], a1, 0, 0, 0);
            int gmt = ch * 8 + mt;
#pragma unroll
            for (int r = 0; r < 4; ++r) {   // strict > : ascending k keeps first max
                if (a0[r] > best[0][r]) { best[0][r] = a0[r]; bmt[0][r] = gmt; }
                if (a1[r] > best[1][r]) { best[1][r] = a1[r]; bmt[1][r] = gmt; }
            }
        }
    }

    // ---- epilogue: lex-reduce (score desc, k asc), write idx/quantized/loss ----
    float lsum = 0.f;
#pragma unroll
    for (int t = 0; t < 2; ++t) {
        float bs = best[t][0];
        int   bk = bmt[t][0] * 16 + g * 4 + 0;
#pragma unroll
        for (int r = 1; r < 4; ++r) {
            float sc = best[t][r];
            int   k  = bmt[t][r] * 16 + g * 4 + r;
            if (sc > bs || (sc == bs && k < bk)) { bs = sc; bk = k; }
        }
#pragma unroll
        for (int m = 16; m <= 32; m <<= 1) {
            float os = __shfl_xor(bs, m);
            int   ok = __shfl_xor(bk, m);
            if (os > bs || (os == bs && ok < bk)) { bs = os; bk = ok; }
        }
        int pos = p0 + wv * 32 + t * 16 + col;
        int sp  = pos & 32767;
        if (g == 0) out[OUT_IDX + pos] = (float)bk;
        const float* eb = emb + (size_t)bk * CDIM;
        float* q = out + OUT_Q + (size_t)b * (CDIM * SPATIAL) + sp;
#pragma unroll
        for (int s = 0; s < 2; ++s)
#pragma unroll
            for (int i = 0; i < 8; ++i) {
                int c = s * 32 + g * 8 + i;
                float x = (float)bh[t][s][i] + (float)bl[t][s][i];  // |x'-x| <= 2^-22|x|
                float e = eb[c];
                float d = e - x;                                    // stop_grad(q - x)
                lsum = fmaf(d, d, lsum);
                q[(size_t)c * SPATIAL] = x + d;                     // straight-through
            }
    }
#pragma unroll
    for (int off = 32; off > 0; off >>= 1) lsum += __shfl_down(lsum, off);
    if (lane == 0) atomicAdd(out + OUT_LOSS, lsum * (0.25f / (float)NEL));
}

extern "C" void kernel_launch(void* const* d_in, const int* in_sizes, int n_in,
                              void* d_out, int out_size, void* d_ws, size_t ws_size,
                              hipStream_t stream) {
    const float* in  = (const float*)d_in[0];   // [2,64,32,32,32] f32
    const float* emb = (const float*)d_in[1];   // [1024,64] f32
    float* out = (float*)d_out;
    char*  ws  = (char*)d_ws;                   // 266,240 B used

    prep_emb<<<KCODES / 256, 256, 0, stream>>>(emb, ws);
    init_kernel<<<1, 256, 0, stream>>>(out);
    vq_kernel<<<NPOS / 128, 256, 0, stream>>>(in, emb, ws, out);

    hipMemcpyAsync(out + OUT_EMB, emb, (size_t)KCODES * CDIM * sizeof(float),
                   hipMemcpyDeviceToDevice, stream);
}

// Round 3
// 63.101 us; speedup vs baseline: 24.2984x; 1.4788x over previous
//
#include <hip/hip_runtime.h>
#include <stdint.h>

#define KCODES  1024
#define CDIM    64
#define SPATIAL 32768
#define NPOS    65536
#define NEL     4194304

// d_out layout (floats), outputs concatenated in reference return order
#define OUT_Q    0
#define OUT_LOSS 4194304
#define OUT_IDX  4194305
#define OUT_SUM  4259841
#define OUT_EMB  4260097

// ws: 8 chunks x {hi frags 16KB | lo frags 16KB | -0.5*||e||^2 512B}
#define REC_BYTES 33280
#define BPOS 64            // positions per block

typedef _Float16 half8 __attribute__((ext_vector_type(8)));
typedef float    f32x4 __attribute__((ext_vector_type(4)));

// ---- prep: fragment-swizzle codebook, zero loss/encodings_sum, emb passthrough ----
__global__ void prep_emb(const float* __restrict__ emb, char* __restrict__ ws,
                         float* __restrict__ out) {
    int k = blockIdx.x * blockDim.x + threadIdx.x;   // 4 blocks x 256 = 1024
    if (blockIdx.x == 0) {
        if (threadIdx.x == 0) out[OUT_LOSS] = 0.f;
        out[OUT_SUM + threadIdx.x] = 0.f;            // 256 threads cover 256 slots
    }
    // embedding passthrough (OUT_EMB is odd offset -> scalar coalesced copy)
    for (int i = k; i < KCODES * CDIM; i += 1024)
        out[OUT_EMB + i] = emb[i];
    // fragment swizzle
    const float* e = emb + (size_t)k * CDIM;
    int ch = k >> 7, mt = (k >> 4) & 7, row = k & 15;
    char* rec = ws + (size_t)ch * REC_BYTES;
    _Float16* hi = (_Float16*)rec;
    _Float16* lo = hi + 8192;
    float* ens = (float*)(rec + 32768);
    float s2 = 0.f;
    for (int c = 0; c < CDIM; ++c) {
        float v = e[c];
        s2 = fmaf(v, v, s2);
        _Float16 h = (_Float16)v;
        _Float16 l = (_Float16)(v - (float)h);
        int s = c >> 5, g = (c >> 3) & 3, i = c & 7;
        int off = (mt * 2 + s) * 512 + ((g << 4) | row) * 8 + i;  // lane-linear
        hi[off] = h;
        lo[off] = l;
    }
    ens[k & 127] = -0.5f * s2;
}

// ---- main VQ kernel ----
// Block: 256 thr = 4 waves, 64 positions (4 N-tiles of 16 per wave).
// K-split: wave w scans codes [w*256, w*256+256) = 16 mt-tiles, A-frags direct from L2.
// Score = x.e - 0.5||e||^2 (C-init), argmax == argmin distance. No main-loop barriers.
__global__ __launch_bounds__(256, 3) void vq_kernel(
        const float* __restrict__ in, const float* __restrict__ emb,
        const char* __restrict__ wsA, float* __restrict__ out) {
    __shared__ float xl[CDIM * 65];        // x tile [c][pos], pitch 65 (16640 B)
    __shared__ float redS[4][4][16];       // wave, tile, col
    __shared__ int   redK[4][4][16];
    __shared__ int   kwin[BPOS];

    const int tid  = threadIdx.x;
    const int lane = tid & 63, wv = tid >> 6;
    const int g = lane >> 4, col = lane & 15;
    const int p0 = blockIdx.x * BPOS;
    const int b  = p0 >> 15;               // 64-pos tile never straddles batch
    const int s0 = p0 & 32767;
    const float* xin = in + (size_t)b * (CDIM * SPATIAL) + s0;

    // phase A: x tile -> LDS f32 [c][pos] (coalesced 256B reads, conflict-free writes)
    {
        int p = tid & 63, cq = tid >> 6;
#pragma unroll
        for (int j = 0; j < 16; ++j) {
            int c = cq * 16 + j;
            xl[c * 65 + p] = xin[(size_t)c * SPATIAL + p];
        }
    }
    __syncthreads();

    // phase B: per-wave B-fragments (positions) hi/lo fp16
    half8 bh[4][2], bl[4][2];
#pragma unroll
    for (int t = 0; t < 4; ++t)
#pragma unroll
        for (int s = 0; s < 2; ++s) {
            int p = t * 16 + col;
#pragma unroll
            for (int i = 0; i < 8; ++i) {
                int c = s * 32 + g * 8 + i;
                float v = xl[c * 65 + p];
                _Float16 h = (_Float16)v;
                bh[t][s][i] = h;
                bl[t][s][i] = (_Float16)(v - (float)h);
            }
        }

    float best[4][4];
    int   bmt[4][4];
#pragma unroll
    for (int t = 0; t < 4; ++t)
#pragma unroll
        for (int r = 0; r < 4; ++r) { best[t][r] = -3.402823466e38f; bmt[t][r] = 0; }

    // main loop: 2 chunks x 8 mt, A-frags streamed from L2 (no barriers)
    const char* base = wsA + (size_t)(wv * 2) * REC_BYTES;
    for (int ch = 0; ch < 2; ++ch) {
        const char* rec = base + (size_t)ch * REC_BYTES;
#pragma unroll
        for (int mt = 0; mt < 8; ++mt) {
            const char* hp = rec + mt * 2048 + (size_t)lane * 16;
            half8 ah0 = *(const half8*)(hp);
            half8 ah1 = *(const half8*)(hp + 1024);
            half8 al0 = *(const half8*)(hp + 16384);
            half8 al1 = *(const half8*)(hp + 16384 + 1024);
            f32x4 ei  = *(const f32x4*)(rec + 32768 + mt * 64 + g * 16);
            int gmt = ch * 8 + mt;
#pragma unroll
            for (int t = 0; t < 4; ++t) {
                f32x4 a = ei;
                a = __builtin_amdgcn_mfma_f32_16x16x32_f16(ah0, bh[t][0], a, 0, 0, 0);
                a = __builtin_amdgcn_mfma_f32_16x16x32_f16(ah1, bh[t][1], a, 0, 0, 0);
                a = __builtin_amdgcn_mfma_f32_16x16x32_f16(ah0, bl[t][0], a, 0, 0, 0);
                a = __builtin_amdgcn_mfma_f32_16x16x32_f16(ah1, bl[t][1], a, 0, 0, 0);
                a = __builtin_amdgcn_mfma_f32_16x16x32_f16(al0, bh[t][0], a, 0, 0, 0);
                a = __builtin_amdgcn_mfma_f32_16x16x32_f16(al1, bh[t][1], a, 0, 0, 0);
#pragma unroll
                for (int r = 0; r < 4; ++r)
                    if (a[r] > best[t][r]) { best[t][r] = a[r]; bmt[t][r] = gmt; }
            }
        }
    }

    // per-wave lex-reduce (score desc, k asc) -> LDS
#pragma unroll
    for (int t = 0; t < 4; ++t) {
        float bs = best[t][0];
        int   bk = wv * 256 + bmt[t][0] * 16 + g * 4 + 0;
#pragma unroll
        for (int r = 1; r < 4; ++r) {
            float sc = best[t][r];
            int   k  = wv * 256 + bmt[t][r] * 16 + g * 4 + r;
            if (sc > bs || (sc == bs && k < bk)) { bs = sc; bk = k; }
        }
#pragma unroll
        for (int m = 16; m <= 32; m <<= 1) {
            float os = __shfl_xor(bs, m);
            int   ok = __shfl_xor(bk, m);
            if (os > bs || (os == bs && ok < bk)) { bs = os; bk = ok; }
        }
        if (g == 0) { redS[wv][t][col] = bs; redK[wv][t][col] = bk; }
    }
    __syncthreads();

    // cross-wave reduce (wave 0), write indices coalesced, publish winners
    if (wv == 0) {
        int t = lane >> 4, c2 = lane & 15;
        float bs = redS[0][t][c2];
        int   bk = redK[0][t][c2];
#pragma unroll
        for (int w = 1; w < 4; ++w) {
            float sc = redS[w][t][c2];
            int   k  = redK[w][t][c2];
            if (sc > bs || (sc == bs && k < bk)) { bs = sc; bk = k; }
        }
        kwin[lane] = bk;
        out[OUT_IDX + p0 + lane] = (float)bk;
    }
    __syncthreads();

    // epilogue: coalesced q stores (lane = position), exact f32 x from LDS
    float lsum = 0.f;
    {
        int p = tid & 63, cq = tid >> 6;
        int kk = kwin[p];
        const float* eb = emb + (size_t)kk * CDIM;     // L1/L2 gather
        float* q = out + OUT_Q + (size_t)b * (CDIM * SPATIAL) + s0;
#pragma unroll
        for (int j = 0; j < 16; ++j) {
            int c = cq * 16 + j;
            float e = eb[c];
            float x = xl[c * 65 + p];
            float d = e - x;                           // stop_grad(q - x)
            lsum = fmaf(d, d, lsum);
            q[(size_t)c * SPATIAL + p] = x + d;        // straight-through, 256B/wave store
        }
    }
#pragma unroll
    for (int off = 32; off > 0; off >>= 1) lsum += __shfl_down(lsum, off);
    if (lane == 0) redS[wv][0][0] = lsum;
    __syncthreads();
    if (tid == 0) {
        float t = redS[0][0][0] + redS[1][0][0] + redS[2][0][0] + redS[3][0][0];
        atomicAdd(out + OUT_LOSS, t * (0.25f / (float)NEL));
    }
}

extern "C" void kernel_launch(void* const* d_in, const int* in_sizes, int n_in,
                              void* d_out, int out_size, void* d_ws, size_t ws_size,
                              hipStream_t stream) {
    const float* in  = (const float*)d_in[0];   // [2,64,32,32,32] f32
    const float* emb = (const float*)d_in[1];   // [1024,64] f32
    float* out = (float*)d_out;
    char*  ws  = (char*)d_ws;                   // 266,240 B used

    prep_emb<<<KCODES / 256, 256, 0, stream>>>(emb, ws, out);
    vq_kernel<<<NPOS / BPOS, 256, 0, stream>>>(in, emb, ws, out);
}